// Round 15
// baseline (1157.538 us; speedup 1.0000x reference)
//
#include <hip/hip_runtime.h>
#include <hip/hip_bf16.h>
#include <hip/hip_cooperative_groups.h>

namespace cg = cooperative_groups;

#define NODE_IN 128
#define EDGE_INF 128
#define HIDW 256
#define OUT_D 128
#define IN_DIM 512
#define EPSLN 1e-5f

using f32x4 = __attribute__((ext_vector_type(4))) float;
using bfv8  = __attribute__((ext_vector_type(8))) __bf16;

static __device__ __forceinline__ unsigned short f2bf(float f){
    union { float f; unsigned int u; } x; x.f = f;
    unsigned int r = x.u + 0x7fffu + ((x.u >> 16) & 1u);
    return (unsigned short)(r >> 16);
}

static __device__ __forceinline__ f32x4 mfma16(bfv8 a, bfv8 b, f32x4 c){
    return __builtin_amdgcn_mfma_f32_16x16x32_bf16(a, b, c, 0, 0, 0);
}

// ---------- cooperative prep: zero + wconv + count + scan + scatter (1 dispatch) ----------
// weight tiling: chunk c = kt*NT + t holds 512 shorts: lane l (lr=l&15,lg=l>>4), elem e:
//   value = bf16( W[k][n] ), k = kt*32 + lg*8 + e, n = t*16 + lr
__global__ void k_prep(const float* __restrict__ W0, const float* __restrict__ W1,
                       const float* __restrict__ W2, const float* __restrict__ W3,
                       unsigned short* __restrict__ W0t, unsigned short* __restrict__ W1t,
                       unsigned short* __restrict__ W2t, unsigned short* __restrict__ W3t,
                       const int* __restrict__ col, int* __restrict__ deg,
                       int* __restrict__ indptr, int* __restrict__ cursor,
                       int* __restrict__ edge_of, int* __restrict__ bsum,
                       int N, int E, int nb)
{
    cg::grid_group grid = cg::this_grid();
    __shared__ int sbuf[256];
    int t   = threadIdx.x;
    int tid = blockIdx.x*256 + t;
    int stride = gridDim.x*256;

    // ---- phase 0: zero deg + weight convert ----
    for(int i = tid; i < N; i += stride) deg[i] = 0;
    for(int idx = tid; idx < 294912; idx += stride){
        const float* W; unsigned short* Wt; int Nc, NT, off;
        if(idx < 131072){ W=W0; Wt=W0t; Nc=256; NT=16; off=idx; }
        else if(idx < 196608){ W=W1; Wt=W1t; Nc=256; NT=16; off=idx-131072; }
        else if(idx < 262144){ W=W2; Wt=W2t; Nc=256; NT=16; off=idx-196608; }
        else { W=W3; Wt=W3t; Nc=128; NT=8;  off=idx-262144; }
        int e  = off & 7;
        int l  = (off >> 3) & 63;
        int c  = off >> 9;
        int kt = c / NT, tt = c - kt*NT;
        int lr = l & 15, lg = l >> 4;
        int k  = kt*32 + lg*8 + e;
        int n  = tt*16 + lr;
        Wt[off] = f2bf(W[(size_t)k*Nc + n]);
    }
    grid.sync();

    // ---- phase 1: degree count ----
    for(int e = tid; e < E; e += stride) atomicAdd(&deg[col[e]], 1);
    grid.sync();

    // ---- phase 2: per-1024-chunk block sums ----
    if((int)blockIdx.x < nb){
        int base = blockIdx.x*1024 + t*4;
        int v0=0,v1=0,v2=0,v3=0;
        if(base + 3 < N){ int4 q = *reinterpret_cast<const int4*>(deg+base); v0=q.x;v1=q.y;v2=q.z;v3=q.w; }
        else { if(base<N)v0=deg[base]; if(base+1<N)v1=deg[base+1]; if(base+2<N)v2=deg[base+2]; if(base+3<N)v3=deg[base+3]; }
        sbuf[t] = v0+v1+v2+v3; __syncthreads();
        for(int off=128; off>0; off>>=1){ if(t<off) sbuf[t]+=sbuf[t+off]; __syncthreads(); }
        if(t==0) bsum[blockIdx.x] = sbuf[0];
    }
    grid.sync();

    // ---- phase 3: exclusive scan of block sums (block 0) ----
    if(blockIdx.x == 0){
        int v = (t<nb)? bsum[t] : 0;
        sbuf[t]=v; __syncthreads();
        for(int off=1; off<256; off<<=1){
            int u = (t>=off)? sbuf[t-off] : 0;
            __syncthreads();
            sbuf[t] += u;
            __syncthreads();
        }
        if(t<nb) bsum[t] = sbuf[t]-v;   // exclusive
    }
    grid.sync();

    // ---- phase 4: indptr / cursor ----
    if((int)blockIdx.x < nb){
        int base = blockIdx.x*1024 + t*4;
        int v[4] = {0,0,0,0};
        if(base + 3 < N){ int4 q = *reinterpret_cast<const int4*>(deg+base); v[0]=q.x;v[1]=q.y;v[2]=q.z;v[3]=q.w; }
        else { for(int j=0;j<4;j++) if(base+j<N) v[j]=deg[base+j]; }
        int s = v[0]+v[1]+v[2]+v[3];
        sbuf[t] = s; __syncthreads();
        for(int off=1; off<256; off<<=1){
            int u = (t>=off)? sbuf[t-off] : 0;
            __syncthreads();
            sbuf[t] += u;
            __syncthreads();
        }
        int p = bsum[blockIdx.x] + sbuf[t] - s;
        #pragma unroll
        for(int j=0;j<4;j++){
            int idx = base+j;
            if(idx < N){
                indptr[idx]=p; cursor[idx]=p;
                if(idx==N-1) indptr[N]=p+v[j];
                p += v[j];
            }
        }
    }
    grid.sync();

    // ---- phase 5: scatter edge ids ----
    for(int e = tid; e < E; e += stride){
        int pos = atomicAdd(&cursor[col[e]], 1);
        edge_of[pos] = e;
    }
}

// ---------- gather: one wave per node; lane-halves cover 2 edges via float4 ----------
__global__ __launch_bounds__(256) void k_gather(
        const int* __restrict__ indptr, const int* __restrict__ edge_of,
        const float* __restrict__ eattr, const float* __restrict__ x,
        unsigned short* __restrict__ h0, int n){
    int node = blockIdx.x*4 + (threadIdx.x >> 6);
    if(node >= n) return;
    int l = threadIdx.x & 63;
    int half = l >> 5;
    int fi = (l & 31) * 4;
    int s = indptr[node], e = indptr[node+1];
    float s0=0.f,s1=0.f,s2=0.f,s3=0.f;
    float m0=-INFINITY,m1=-INFINITY,m2=-INFINITY,m3=-INFINITY;
    int p = s + half;
    for(; p + 2 < e; p += 4){
        int e0 = edge_of[p], e1 = edge_of[p+2];
        float4 v0 = *reinterpret_cast<const float4*>(eattr + (size_t)e0*EDGE_INF + fi);
        float4 v1 = *reinterpret_cast<const float4*>(eattr + (size_t)e1*EDGE_INF + fi);
        s0 += v0.x + v1.x; s1 += v0.y + v1.y; s2 += v0.z + v1.z; s3 += v0.w + v1.w;
        m0 = fmaxf(m0, fmaxf(v0.x, v1.x)); m1 = fmaxf(m1, fmaxf(v0.y, v1.y));
        m2 = fmaxf(m2, fmaxf(v0.z, v1.z)); m3 = fmaxf(m3, fmaxf(v0.w, v1.w));
    }
    if(p < e){
        int e0 = edge_of[p];
        float4 v0 = *reinterpret_cast<const float4*>(eattr + (size_t)e0*EDGE_INF + fi);
        s0 += v0.x; s1 += v0.y; s2 += v0.z; s3 += v0.w;
        m0 = fmaxf(m0, v0.x); m1 = fmaxf(m1, v0.y); m2 = fmaxf(m2, v0.z); m3 = fmaxf(m3, v0.w);
    }
    s0 += __shfl_xor(s0, 32); s1 += __shfl_xor(s1, 32);
    s2 += __shfl_xor(s2, 32); s3 += __shfl_xor(s3, 32);
    m0 = fmaxf(m0, __shfl_xor(m0, 32)); m1 = fmaxf(m1, __shfl_xor(m1, 32));
    m2 = fmaxf(m2, __shfl_xor(m2, 32)); m3 = fmaxf(m3, __shfl_xor(m3, 32));
    int d = e - s;
    float inv = 1.f / fmaxf((float)d, 1.f);
    if(d == 0){ m0=0.f; m1=0.f; m2=0.f; m3=0.f; }
    if(half == 0){
        float4 xv = *reinterpret_cast<const float4*>(x + (size_t)node*NODE_IN + fi);
        size_t r = (size_t)node * IN_DIM;
        ushort4 u;
        u.x=f2bf(s0); u.y=f2bf(s1); u.z=f2bf(s2); u.w=f2bf(s3);
        *reinterpret_cast<ushort4*>(h0 + r + fi) = u;
        u.x=f2bf(m0); u.y=f2bf(m1); u.z=f2bf(m2); u.w=f2bf(m3);
        *reinterpret_cast<ushort4*>(h0 + r + 128 + fi) = u;
        u.x=f2bf(s0*inv); u.y=f2bf(s1*inv); u.z=f2bf(s2*inv); u.w=f2bf(s3*inv);
        *reinterpret_cast<ushort4*>(h0 + r + 256 + fi) = u;
        u.x=f2bf(xv.x); u.y=f2bf(xv.y); u.z=f2bf(xv.z); u.w=f2bf(xv.w);
        *reinterpret_cast<ushort4*>(h0 + r + 384 + fi) = u;
    }
}

// ---------- fused MLP (R6 structure: rolled kt-loops, tiled staging, dbuf wt) ----------
template<int NT>
static __device__ __forceinline__ void stage_w(const unsigned short* __restrict__ Wtil, int kt,
                                               unsigned short* dst, int w, int l){
    constexpr int TPW = NT/4;
    #pragma unroll
    for(int i=0;i<TPW;i++){
        int t = w*TPW + i;
        const unsigned short* src = Wtil + ((size_t)(kt*NT + t))*512 + l*8;
        __builtin_amdgcn_global_load_lds(
            (const __attribute__((address_space(1))) void*)src,
            (__attribute__((address_space(3))) void*)(dst + (size_t)t*512),
            16, 0, 0);
    }
}

template<int NT>
static __device__ __forceinline__ void ln_silu_store(
    f32x4* acc, const float* __restrict__ bias,
    const float* __restrict__ g, const float* __restrict__ be,
    __bf16* __restrict__ hrow, int l)
{
    int lr = l & 15, lg = l >> 4;
    float s[4] = {0,0,0,0}, q[4] = {0,0,0,0};
    #pragma unroll
    for(int t=0;t<NT;t++){
        float b = bias[t*16 + lr];
        #pragma unroll
        for(int j=0;j<4;j++){
            float z = acc[t][j] + b;
            acc[t][j] = z;
            s[j] += z; q[j] += z*z;
        }
    }
    #pragma unroll
    for(int m=1;m<16;m<<=1){
        #pragma unroll
        for(int j=0;j<4;j++){
            s[j] += __shfl_xor(s[j], m, 64);
            q[j] += __shfl_xor(q[j], m, 64);
        }
    }
    float mean[4], inv[4];
    #pragma unroll
    for(int j=0;j<4;j++){
        mean[j] = s[j] * (1.f/256.f);
        float var = q[j] * (1.f/256.f) - mean[j]*mean[j];
        inv[j] = rsqrtf(var + EPSLN);
    }
    #pragma unroll
    for(int t=0;t<NT;t++){
        int colb = t*16 + lr;
        float gg = g[colb], bb = be[colb];
        #pragma unroll
        for(int j=0;j<4;j++){
            int row = lg*4 + j;
            float y = (acc[t][j] - mean[j]) * inv[j] * gg + bb;
            float sil = y / (1.f + __expf(-y));
            int chunk = (colb >> 3) ^ (row & 7);
            hrow[row*256 + chunk*8 + (colb & 7)] = (__bf16)sil;
        }
    }
}

__global__ __launch_bounds__(256, 2) void k_mlp(
    const unsigned short* __restrict__ h0,
    const unsigned short* __restrict__ W0t, const float* __restrict__ b0, const float* __restrict__ g0, const float* __restrict__ be0,
    const unsigned short* __restrict__ W1t, const float* __restrict__ b1, const float* __restrict__ g1, const float* __restrict__ be1,
    const unsigned short* __restrict__ W2t, const float* __restrict__ b2, const float* __restrict__ g2, const float* __restrict__ be2,
    const unsigned short* __restrict__ W3t, const float* __restrict__ b3,
    float* __restrict__ out, int n)
{
    __shared__ __bf16 hb[4][16][256];            // 32 KB
    __shared__ unsigned short wt[2][16*512];     // 32 KB, double-buffered weight tile
    int w = threadIdx.x >> 6;
    int l = threadIdx.x & 63;
    int lr = l & 15, lg = l >> 4;
    int row0 = blockIdx.x*64 + w*16;
    __bf16* hrow = &hb[w][0][0];

    f32x4 acc[16];
    f32x4 zero = {0.f,0.f,0.f,0.f};

    // ---- L0: [16 x 512] @ [512 x 256]; A via 2-deep register pipeline (rolled) ----
    #pragma unroll
    for(int t=0;t<16;t++) acc[t] = zero;
    const unsigned short* ap = h0 + (size_t)(row0 + lr)*IN_DIM + lg*8;
    stage_w<16>(W0t, 0, wt[0], w, l);
    bfv8 a_cur = *reinterpret_cast<const bfv8*>(ap);
    __syncthreads();
    #pragma unroll 1
    for(int kt=0; kt<16; kt++){
        bfv8 a_nxt = a_cur;
        if(kt < 15){
            stage_w<16>(W0t, kt+1, wt[(kt+1)&1], w, l);
            a_nxt = *reinterpret_cast<const bfv8*>(ap + (kt+1)*32);
        }
        const unsigned short* wb = wt[kt&1] + l*8;
        #pragma unroll
        for(int t=0;t<16;t++){
            bfv8 b = *reinterpret_cast<const bfv8*>(wb + t*512);
            acc[t] = mfma16(a_cur, b, acc[t]);
        }
        a_cur = a_nxt;
        __syncthreads();
    }
    ln_silu_store<16>(acc, b0, g0, be0, hrow, l);

    // ---- L1 & L2 share one rolled loop body ----
    #pragma unroll 1
    for(int li=0; li<2; li++){
        const unsigned short* Wt = li ? W2t : W1t;
        const float* bi  = li ? b2  : b1;
        const float* gi  = li ? g2  : g1;
        const float* bei = li ? be2 : be1;
        #pragma unroll
        for(int t=0;t<16;t++) acc[t] = zero;
        stage_w<16>(Wt, 0, wt[0], w, l);
        __syncthreads();
        #pragma unroll 1
        for(int kt=0; kt<8; kt++){
            if(kt < 7) stage_w<16>(Wt, kt+1, wt[(kt+1)&1], w, l);
            int chunk = (kt*4 + lg) ^ (lr & 7);
            bfv8 av = *reinterpret_cast<const bfv8*>(hrow + lr*256 + chunk*8);
            const unsigned short* wb = wt[kt&1] + l*8;
            #pragma unroll
            for(int t=0;t<16;t++){
                bfv8 b = *reinterpret_cast<const bfv8*>(wb + t*512);
                acc[t] = mfma16(av, b, acc[t]);
            }
            __syncthreads();
        }
        ln_silu_store<16>(acc, bi, gi, bei, hrow, l);
    }

    // ---- L3: [16 x 256] @ [256 x 128] (rolled) ----
    #pragma unroll
    for(int t=0;t<8;t++) acc[t] = zero;
    stage_w<8>(W3t, 0, wt[0], w, l);
    __syncthreads();
    #pragma unroll 1
    for(int kt=0; kt<8; kt++){
        if(kt < 7) stage_w<8>(W3t, kt+1, wt[(kt+1)&1], w, l);
        int chunk = (kt*4 + lg) ^ (lr & 7);
        bfv8 av = *reinterpret_cast<const bfv8*>(hrow + lr*256 + chunk*8);
        const unsigned short* wb = wt[kt&1] + l*8;
        #pragma unroll
        for(int t=0;t<8;t++){
            bfv8 b = *reinterpret_cast<const bfv8*>(wb + t*512);
            acc[t] = mfma16(av, b, acc[t]);
        }
        __syncthreads();
    }
    #pragma unroll
    for(int t=0;t<8;t++){
        int col = t*16 + lr;
        float bb = b3[col];
        #pragma unroll
        for(int j=0;j<4;j++){
            int grow = row0 + lg*4 + j;
            if(grow < n) out[(size_t)grow*OUT_D + col] = acc[t][j] + bb;
        }
    }
}

extern "C" void kernel_launch(void* const* d_in, const int* in_sizes, int n_in,
                              void* d_out, int out_size, void* d_ws, size_t ws_size,
                              hipStream_t stream)
{
    const float* x          = (const float*)d_in[0];
    const int*   edge_index = (const int*)d_in[1];
    const float* edge_attr  = (const float*)d_in[2];
    const float* W0  = (const float*)d_in[5];
    const float* b0  = (const float*)d_in[6];
    const float* g0  = (const float*)d_in[7];
    const float* be0 = (const float*)d_in[8];
    const float* W1  = (const float*)d_in[9];
    const float* b1  = (const float*)d_in[10];
    const float* g1  = (const float*)d_in[11];
    const float* be1 = (const float*)d_in[12];
    const float* W2  = (const float*)d_in[13];
    const float* b2  = (const float*)d_in[14];
    const float* g2  = (const float*)d_in[15];
    const float* be2 = (const float*)d_in[16];
    const float* W3  = (const float*)d_in[17];
    const float* b3  = (const float*)d_in[18];

    int N = in_sizes[0] / NODE_IN;
    int E = in_sizes[2] / EDGE_INF;
    const int* col = edge_index + E;

    char* p = (char*)d_ws;
    auto alloc = [&](size_t bytes) -> char* {
        char* r = p; p += (bytes + 255) & ~(size_t)255; return r;
    };
    int* deg     = (int*)alloc((size_t)N*4);
    int* indptr  = (int*)alloc((size_t)(N+1)*4);
    int* cursor  = (int*)alloc((size_t)N*4);
    int* edge_of = (int*)alloc((size_t)E*4);
    int nb = (N + 1023) / 1024;
    int* bsum    = (int*)alloc((size_t)nb*4);
    int Mpad = ((N + 63)/64)*64;
    unsigned short* h0  = (unsigned short*)alloc((size_t)Mpad*IN_DIM*2);
    unsigned short* W0t = (unsigned short*)alloc((size_t)IN_DIM*HIDW*2);
    unsigned short* W1t = (unsigned short*)alloc((size_t)HIDW*HIDW*2);
    unsigned short* W2t = (unsigned short*)alloc((size_t)HIDW*HIDW*2);
    unsigned short* W3t = (unsigned short*)alloc((size_t)HIDW*OUT_D*2);

    // ---- single cooperative prep dispatch (zero+wconv+count+scan+scatter) ----
    void* args[] = {
        (void*)&W0, (void*)&W1, (void*)&W2, (void*)&W3,
        (void*)&W0t, (void*)&W1t, (void*)&W2t, (void*)&W3t,
        (void*)&col, (void*)&deg, (void*)&indptr, (void*)&cursor,
        (void*)&edge_of, (void*)&bsum, (void*)&N, (void*)&E, (void*)&nb
    };
    hipLaunchCooperativeKernel((const void*)k_prep, dim3(1024), dim3(256), args, 0, stream);

    k_gather<<<(N+3)/4, 256, 0, stream>>>(indptr, edge_of, edge_attr, x, h0, N);

    k_mlp<<<Mpad/64, 256, 0, stream>>>(h0,
        W0t, b0, g0, be0, W1t, b1, g1, be1, W2t, b2, g2, be2, W3t, b3,
        (float*)d_out, N);
}

// Round 16
// 663.952 us; speedup vs baseline: 1.7434x; 1.7434x over previous
//
#include <hip/hip_runtime.h>
#include <hip/hip_bf16.h>

#define NODE_IN 128
#define EDGE_INF 128
#define HIDW 256
#define OUT_D 128
#define IN_DIM 512
#define EPSLN 1e-5f

using f32x4 = __attribute__((ext_vector_type(4))) float;
using bfv8  = __attribute__((ext_vector_type(8))) __bf16;

static __device__ __forceinline__ unsigned short f2bf(float f){
    union { float f; unsigned int u; } x; x.f = f;
    unsigned int r = x.u + 0x7fffu + ((x.u >> 16) & 1u);
    return (unsigned short)(r >> 16);
}

static __device__ __forceinline__ f32x4 mfma16(bfv8 a, bfv8 b, f32x4 c){
    return __builtin_amdgcn_mfma_f32_16x16x32_bf16(a, b, c, 0, 0, 0);
}

// ---------- fused: degree count + weight convert (independent tasks, one dispatch) ----------
// weight tiling: chunk c = kt*NT + t holds 512 shorts: lane l (lr=l&15,lg=l>>4), elem e:
//   value = bf16( W[k][n] ), k = kt*32 + lg*8 + e, n = t*16 + lr
__global__ void k_count_wconv(const int* __restrict__ col, int* __restrict__ deg, int E,
                              const float* __restrict__ W0, const float* __restrict__ W1,
                              const float* __restrict__ W2, const float* __restrict__ W3,
                              unsigned short* __restrict__ W0t, unsigned short* __restrict__ W1t,
                              unsigned short* __restrict__ W2t, unsigned short* __restrict__ W3t){
    int tid = blockIdx.x*256 + threadIdx.x;
    if(tid < E) atomicAdd(&deg[col[tid]], 1);
    if(tid < 294912){
        int idx = tid;
        const float* W; unsigned short* Wt; int Nc, NT, off;
        if(idx < 131072){ W=W0; Wt=W0t; Nc=256; NT=16; off=idx; }
        else if(idx < 196608){ W=W1; Wt=W1t; Nc=256; NT=16; off=idx-131072; }
        else if(idx < 262144){ W=W2; Wt=W2t; Nc=256; NT=16; off=idx-196608; }
        else { W=W3; Wt=W3t; Nc=128; NT=8;  off=idx-262144; }
        int e  = off & 7;
        int l  = (off >> 3) & 63;
        int c  = off >> 9;
        int kt = c / NT, t = c - kt*NT;
        int lr = l & 15, lg = l >> 4;
        int k  = kt*32 + lg*8 + e;
        int n  = t*16 + lr;
        Wt[off] = f2bf(W[(size_t)k*Nc + n]);
    }
}

// ---------- single-block coalesced exclusive scan (replaces scan1/scan2/scan3) ----------
__global__ __launch_bounds__(1024) void k_scan(const int* __restrict__ deg,
                                               int* __restrict__ indptr, int* __restrict__ cursor,
                                               int n){
    __shared__ int wsum[16];
    __shared__ int carry_s;
    int t = threadIdx.x;
    int lane = t & 63, wid = t >> 6;
    if(t == 0) carry_s = 0;
    __syncthreads();
    for(int base = 0; base < n; base += 4096){
        int idx = base + t*4;
        int v[4] = {0,0,0,0};
        if(idx + 3 < n){ int4 q = *reinterpret_cast<const int4*>(deg + idx); v[0]=q.x;v[1]=q.y;v[2]=q.z;v[3]=q.w; }
        else { for(int j=0;j<4;j++) if(idx+j < n) v[j] = deg[idx+j]; }
        int s = v[0]+v[1]+v[2]+v[3];
        // intra-wave inclusive scan of per-thread sums
        int ps = s;
        #pragma unroll
        for(int o=1; o<64; o<<=1){
            int u = __shfl_up(ps, o, 64);
            if(lane >= o) ps += u;
        }
        if(lane == 63) wsum[wid] = ps;
        __syncthreads();
        // wave 0 scans the 16 wave totals (exclusive)
        if(wid == 0 && lane < 16){
            int ws = wsum[lane];
            int pw = ws;
            #pragma unroll
            for(int o=1; o<16; o<<=1){
                int u = __shfl_up(pw, o, 16);
                if(lane >= o) pw += u;
            }
            wsum[lane] = pw - ws;
        }
        __syncthreads();
        int carry = carry_s;
        int excl = carry + wsum[wid] + ps - s;
        int p = excl;
        #pragma unroll
        for(int j=0;j<4;j++){
            int id2 = idx + j;
            if(id2 < n){
                indptr[id2] = p; cursor[id2] = p;
                p += v[j];
                if(id2 == n-1) indptr[n] = p;
            }
        }
        __syncthreads();
        if(t == 1023) carry_s = excl + s;
        __syncthreads();
    }
}

__global__ void k_scatter(const int* __restrict__ col, int* __restrict__ cursor,
                          int* __restrict__ edge_of, int E){
    int e = blockIdx.x*256 + threadIdx.x;
    if(e < E){ int pos = atomicAdd(&cursor[col[e]], 1); edge_of[pos] = e; }
}

// ---------- gather: one wave per node; lane-halves cover 2 edges via float4 ----------
__global__ __launch_bounds__(256) void k_gather(
        const int* __restrict__ indptr, const int* __restrict__ edge_of,
        const float* __restrict__ eattr, const float* __restrict__ x,
        unsigned short* __restrict__ h0, int n){
    int node = blockIdx.x*4 + (threadIdx.x >> 6);
    if(node >= n) return;
    int l = threadIdx.x & 63;
    int half = l >> 5;
    int fi = (l & 31) * 4;
    int s = indptr[node], e = indptr[node+1];
    float s0=0.f,s1=0.f,s2=0.f,s3=0.f;
    float m0=-INFINITY,m1=-INFINITY,m2=-INFINITY,m3=-INFINITY;
    int p = s + half;
    for(; p + 2 < e; p += 4){
        int e0 = edge_of[p], e1 = edge_of[p+2];
        float4 v0 = *reinterpret_cast<const float4*>(eattr + (size_t)e0*EDGE_INF + fi);
        float4 v1 = *reinterpret_cast<const float4*>(eattr + (size_t)e1*EDGE_INF + fi);
        s0 += v0.x + v1.x; s1 += v0.y + v1.y; s2 += v0.z + v1.z; s3 += v0.w + v1.w;
        m0 = fmaxf(m0, fmaxf(v0.x, v1.x)); m1 = fmaxf(m1, fmaxf(v0.y, v1.y));
        m2 = fmaxf(m2, fmaxf(v0.z, v1.z)); m3 = fmaxf(m3, fmaxf(v0.w, v1.w));
    }
    if(p < e){
        int e0 = edge_of[p];
        float4 v0 = *reinterpret_cast<const float4*>(eattr + (size_t)e0*EDGE_INF + fi);
        s0 += v0.x; s1 += v0.y; s2 += v0.z; s3 += v0.w;
        m0 = fmaxf(m0, v0.x); m1 = fmaxf(m1, v0.y); m2 = fmaxf(m2, v0.z); m3 = fmaxf(m3, v0.w);
    }
    s0 += __shfl_xor(s0, 32); s1 += __shfl_xor(s1, 32);
    s2 += __shfl_xor(s2, 32); s3 += __shfl_xor(s3, 32);
    m0 = fmaxf(m0, __shfl_xor(m0, 32)); m1 = fmaxf(m1, __shfl_xor(m1, 32));
    m2 = fmaxf(m2, __shfl_xor(m2, 32)); m3 = fmaxf(m3, __shfl_xor(m3, 32));
    int d = e - s;
    float inv = 1.f / fmaxf((float)d, 1.f);
    if(d == 0){ m0=0.f; m1=0.f; m2=0.f; m3=0.f; }
    if(half == 0){
        float4 xv = *reinterpret_cast<const float4*>(x + (size_t)node*NODE_IN + fi);
        size_t r = (size_t)node * IN_DIM;
        ushort4 u;
        u.x=f2bf(s0); u.y=f2bf(s1); u.z=f2bf(s2); u.w=f2bf(s3);
        *reinterpret_cast<ushort4*>(h0 + r + fi) = u;
        u.x=f2bf(m0); u.y=f2bf(m1); u.z=f2bf(m2); u.w=f2bf(m3);
        *reinterpret_cast<ushort4*>(h0 + r + 128 + fi) = u;
        u.x=f2bf(s0*inv); u.y=f2bf(s1*inv); u.z=f2bf(s2*inv); u.w=f2bf(s3*inv);
        *reinterpret_cast<ushort4*>(h0 + r + 256 + fi) = u;
        u.x=f2bf(xv.x); u.y=f2bf(xv.y); u.z=f2bf(xv.z); u.w=f2bf(xv.w);
        *reinterpret_cast<ushort4*>(h0 + r + 384 + fi) = u;
    }
}

// ---------- fused MLP (R6 structure: rolled kt-loops, tiled staging, dbuf wt) ----------
template<int NT>
static __device__ __forceinline__ void stage_w(const unsigned short* __restrict__ Wtil, int kt,
                                               unsigned short* dst, int w, int l){
    constexpr int TPW = NT/4;
    #pragma unroll
    for(int i=0;i<TPW;i++){
        int t = w*TPW + i;
        const unsigned short* src = Wtil + ((size_t)(kt*NT + t))*512 + l*8;
        __builtin_amdgcn_global_load_lds(
            (const __attribute__((address_space(1))) void*)src,
            (__attribute__((address_space(3))) void*)(dst + (size_t)t*512),
            16, 0, 0);
    }
}

template<int NT>
static __device__ __forceinline__ void ln_silu_store(
    f32x4* acc, const float* __restrict__ bias,
    const float* __restrict__ g, const float* __restrict__ be,
    __bf16* __restrict__ hrow, int l)
{
    int lr = l & 15, lg = l >> 4;
    float s[4] = {0,0,0,0}, q[4] = {0,0,0,0};
    #pragma unroll
    for(int t=0;t<NT;t++){
        float b = bias[t*16 + lr];
        #pragma unroll
        for(int j=0;j<4;j++){
            float z = acc[t][j] + b;
            acc[t][j] = z;
            s[j] += z; q[j] += z*z;
        }
    }
    #pragma unroll
    for(int m=1;m<16;m<<=1){
        #pragma unroll
        for(int j=0;j<4;j++){
            s[j] += __shfl_xor(s[j], m, 64);
            q[j] += __shfl_xor(q[j], m, 64);
        }
    }
    float mean[4], inv[4];
    #pragma unroll
    for(int j=0;j<4;j++){
        mean[j] = s[j] * (1.f/256.f);
        float var = q[j] * (1.f/256.f) - mean[j]*mean[j];
        inv[j] = rsqrtf(var + EPSLN);
    }
    #pragma unroll
    for(int t=0;t<NT;t++){
        int colb = t*16 + lr;
        float gg = g[colb], bb = be[colb];
        #pragma unroll
        for(int j=0;j<4;j++){
            int row = lg*4 + j;
            float y = (acc[t][j] - mean[j]) * inv[j] * gg + bb;
            float sil = y / (1.f + __expf(-y));
            int chunk = (colb >> 3) ^ (row & 7);
            hrow[row*256 + chunk*8 + (colb & 7)] = (__bf16)sil;
        }
    }
}

__global__ __launch_bounds__(256, 2) void k_mlp(
    const unsigned short* __restrict__ h0,
    const unsigned short* __restrict__ W0t, const float* __restrict__ b0, const float* __restrict__ g0, const float* __restrict__ be0,
    const unsigned short* __restrict__ W1t, const float* __restrict__ b1, const float* __restrict__ g1, const float* __restrict__ be1,
    const unsigned short* __restrict__ W2t, const float* __restrict__ b2, const float* __restrict__ g2, const float* __restrict__ be2,
    const unsigned short* __restrict__ W3t, const float* __restrict__ b3,
    float* __restrict__ out, int n)
{
    __shared__ __bf16 hb[4][16][256];            // 32 KB
    __shared__ unsigned short wt[2][16*512];     // 32 KB, double-buffered weight tile
    int w = threadIdx.x >> 6;
    int l = threadIdx.x & 63;
    int lr = l & 15, lg = l >> 4;
    int row0 = blockIdx.x*64 + w*16;
    __bf16* hrow = &hb[w][0][0];

    f32x4 acc[16];
    f32x4 zero = {0.f,0.f,0.f,0.f};

    // ---- L0: [16 x 512] @ [512 x 256]; A via 2-deep register pipeline (rolled) ----
    #pragma unroll
    for(int t=0;t<16;t++) acc[t] = zero;
    const unsigned short* ap = h0 + (size_t)(row0 + lr)*IN_DIM + lg*8;
    stage_w<16>(W0t, 0, wt[0], w, l);
    bfv8 a_cur = *reinterpret_cast<const bfv8*>(ap);
    __syncthreads();
    #pragma unroll 1
    for(int kt=0; kt<16; kt++){
        bfv8 a_nxt = a_cur;
        if(kt < 15){
            stage_w<16>(W0t, kt+1, wt[(kt+1)&1], w, l);
            a_nxt = *reinterpret_cast<const bfv8*>(ap + (kt+1)*32);
        }
        const unsigned short* wb = wt[kt&1] + l*8;
        #pragma unroll
        for(int t=0;t<16;t++){
            bfv8 b = *reinterpret_cast<const bfv8*>(wb + t*512);
            acc[t] = mfma16(a_cur, b, acc[t]);
        }
        a_cur = a_nxt;
        __syncthreads();
    }
    ln_silu_store<16>(acc, b0, g0, be0, hrow, l);

    // ---- L1 & L2 share one rolled loop body ----
    #pragma unroll 1
    for(int li=0; li<2; li++){
        const unsigned short* Wt = li ? W2t : W1t;
        const float* bi  = li ? b2  : b1;
        const float* gi  = li ? g2  : g1;
        const float* bei = li ? be2 : be1;
        #pragma unroll
        for(int t=0;t<16;t++) acc[t] = zero;
        stage_w<16>(Wt, 0, wt[0], w, l);
        __syncthreads();
        #pragma unroll 1
        for(int kt=0; kt<8; kt++){
            if(kt < 7) stage_w<16>(Wt, kt+1, wt[(kt+1)&1], w, l);
            int chunk = (kt*4 + lg) ^ (lr & 7);
            bfv8 av = *reinterpret_cast<const bfv8*>(hrow + lr*256 + chunk*8);
            const unsigned short* wb = wt[kt&1] + l*8;
            #pragma unroll
            for(int t=0;t<16;t++){
                bfv8 b = *reinterpret_cast<const bfv8*>(wb + t*512);
                acc[t] = mfma16(av, b, acc[t]);
            }
            __syncthreads();
        }
        ln_silu_store<16>(acc, bi, gi, bei, hrow, l);
    }

    // ---- L3: [16 x 256] @ [256 x 128] (rolled) ----
    #pragma unroll
    for(int t=0;t<8;t++) acc[t] = zero;
    stage_w<8>(W3t, 0, wt[0], w, l);
    __syncthreads();
    #pragma unroll 1
    for(int kt=0; kt<8; kt++){
        if(kt < 7) stage_w<8>(W3t, kt+1, wt[(kt+1)&1], w, l);
        int chunk = (kt*4 + lg) ^ (lr & 7);
        bfv8 av = *reinterpret_cast<const bfv8*>(hrow + lr*256 + chunk*8);
        const unsigned short* wb = wt[kt&1] + l*8;
        #pragma unroll
        for(int t=0;t<8;t++){
            bfv8 b = *reinterpret_cast<const bfv8*>(wb + t*512);
            acc[t] = mfma16(av, b, acc[t]);
        }
        __syncthreads();
    }
    #pragma unroll
    for(int t=0;t<8;t++){
        int col = t*16 + lr;
        float bb = b3[col];
        #pragma unroll
        for(int j=0;j<4;j++){
            int grow = row0 + lg*4 + j;
            if(grow < n) out[(size_t)grow*OUT_D + col] = acc[t][j] + bb;
        }
    }
}

extern "C" void kernel_launch(void* const* d_in, const int* in_sizes, int n_in,
                              void* d_out, int out_size, void* d_ws, size_t ws_size,
                              hipStream_t stream)
{
    const float* x          = (const float*)d_in[0];
    const int*   edge_index = (const int*)d_in[1];
    const float* edge_attr  = (const float*)d_in[2];
    const float* W0  = (const float*)d_in[5];
    const float* b0  = (const float*)d_in[6];
    const float* g0  = (const float*)d_in[7];
    const float* be0 = (const float*)d_in[8];
    const float* W1  = (const float*)d_in[9];
    const float* b1  = (const float*)d_in[10];
    const float* g1  = (const float*)d_in[11];
    const float* be1 = (const float*)d_in[12];
    const float* W2  = (const float*)d_in[13];
    const float* b2  = (const float*)d_in[14];
    const float* g2  = (const float*)d_in[15];
    const float* be2 = (const float*)d_in[16];
    const float* W3  = (const float*)d_in[17];
    const float* b3  = (const float*)d_in[18];

    int N = in_sizes[0] / NODE_IN;
    int E = in_sizes[2] / EDGE_INF;
    const int* col = edge_index + E;

    char* p = (char*)d_ws;
    auto alloc = [&](size_t bytes) -> char* {
        char* r = p; p += (bytes + 255) & ~(size_t)255; return r;
    };
    int* deg     = (int*)alloc((size_t)N*4);
    int* indptr  = (int*)alloc((size_t)(N+1)*4);
    int* cursor  = (int*)alloc((size_t)N*4);
    int* edge_of = (int*)alloc((size_t)E*4);
    int Mpad = ((N + 63)/64)*64;
    unsigned short* h0  = (unsigned short*)alloc((size_t)Mpad*IN_DIM*2);
    unsigned short* W0t = (unsigned short*)alloc((size_t)IN_DIM*HIDW*2);
    unsigned short* W1t = (unsigned short*)alloc((size_t)HIDW*HIDW*2);
    unsigned short* W2t = (unsigned short*)alloc((size_t)HIDW*HIDW*2);
    unsigned short* W3t = (unsigned short*)alloc((size_t)HIDW*OUT_D*2);

    hipMemsetAsync(deg, 0, (size_t)N*4, stream);

    k_count_wconv<<<(E+255)/256, 256, 0, stream>>>(col, deg, E,
        W0, W1, W2, W3, W0t, W1t, W2t, W3t);
    k_scan<<<1, 1024, 0, stream>>>(deg, indptr, cursor, N);
    k_scatter<<<(E+255)/256, 256, 0, stream>>>(col, cursor, edge_of, E);
    k_gather<<<(N+3)/4, 256, 0, stream>>>(indptr, edge_of, edge_attr, x, h0, N);

    k_mlp<<<Mpad/64, 256, 0, stream>>>(h0,
        W0t, b0, g0, be0, W1t, b1, g1, be1, W2t, b2, g2, be2, W3t, b3,
        (float*)d_out, N);
}